// Round 9
// baseline (28457.333 us; speedup 1.0000x reference)
//
#include <hip/hip_runtime.h>
#include <hip/hip_bf16.h>
#include <stdint.h>

typedef __attribute__((ext_vector_type(8))) short short8;
typedef __attribute__((ext_vector_type(4))) float f32x4;
typedef __attribute__((ext_vector_type(4))) unsigned int u32x4;
typedef __attribute__((ext_vector_type(2))) unsigned int u32x2;

__device__ __forceinline__ unsigned short f2bf(float x) {
  unsigned int u = __builtin_bit_cast(unsigned int, x);
  u += 0x7FFFu + ((u >> 16) & 1u);           // round-to-nearest-even
  return (unsigned short)(u >> 16);
}
__device__ __forceinline__ float bf2f(unsigned short u) {
  unsigned int v = ((unsigned int)u) << 16;
  return __builtin_bit_cast(float, v);
}
__device__ __forceinline__ unsigned int pk2(float a, float b) {
  return (unsigned int)f2bf(a) | ((unsigned int)f2bf(b) << 16);
}
__device__ __forceinline__ float sigm(float x) {
  return __builtin_amdgcn_rcpf(1.0f + __builtin_amdgcn_exp2f(-1.44269504f * x));
}
__device__ __forceinline__ float tanh_(float x) {
  return 2.0f * __builtin_amdgcn_rcpf(1.0f + __builtin_amdgcn_exp2f(-2.88539008f * x)) - 1.0f;
}
__device__ __forceinline__ f32x4 mfma16(short8 a, short8 b, f32x4 c) {
  return __builtin_amdgcn_mfma_f32_16x16x32_bf16(a, b, c, 0, 0, 0);
}
__device__ __forceinline__ short8 bc(u32x4 v) { return __builtin_bit_cast(short8, v); }

// ---------------------------------------------------------------------------
// prep: bf16 transposed weight images, fused bias, init 2-domain h ring +
// control block. Gate order: 0=f, 1=i, 2=g, 3=o.
// WxT: [2048 n][512 k]   WhT: [32 wgl][64 j][512 k]  (j = gate*16 + hc_local)
// h ring: 2 domains x 4 slots x [32 rows][512 cols] bf16; slot 0 fresh
// (+0.0), slots 1..3 poison 0x8000 (bf16 -0.0; producers cleanse).
// ctrl: [0]=rank counter, [1..64]=probe (xcc per rank, init -1),
//       [65]=xcc bitmask, [66]=candidate count.
// ---------------------------------------------------------------------------
__global__ void lstm_prep(
    const float* __restrict__ Wif, const float* __restrict__ Wii,
    const float* __restrict__ Wig, const float* __restrict__ Wio,
    const float* __restrict__ Whf, const float* __restrict__ Whi,
    const float* __restrict__ Whg, const float* __restrict__ Who,
    const float* __restrict__ bif, const float* __restrict__ bhf,
    const float* __restrict__ bii, const float* __restrict__ bhi,
    const float* __restrict__ big, const float* __restrict__ bhg,
    const float* __restrict__ bio, const float* __restrict__ bho,
    unsigned short* __restrict__ WxT, unsigned short* __restrict__ WhT,
    float* __restrict__ bias, unsigned short* __restrict__ hring,
    int* __restrict__ ctrl)
{
  const long NWX = 2048L * 512, NWH = 32L * 64 * 512;
  const long NR = 2L * 4 * 32 * 512;           // ring: 131072 ushorts
  long total = NWX + NWH + 2048 + NR + 67;
  for (long i = (long)blockIdx.x * blockDim.x + threadIdx.x; i < total;
       i += (long)gridDim.x * blockDim.x) {
    if (i < NWX) {
      int n = (int)(i >> 9), k = (int)(i & 511);
      int g = n >> 9, hc = n & 511;
      const float* W = (g == 0) ? Wif : (g == 1) ? Wii : (g == 2) ? Wig : Wio;
      WxT[i] = f2bf(W[k * 512 + hc]);
    } else if (i < NWX + NWH) {
      long r = i - NWX;
      int wg = (int)(r >> 15); int rest = (int)(r & 32767);
      int j = rest >> 9, k = rest & 511;
      int g = j >> 4, hc = wg * 16 + (j & 15);
      const float* W = (g == 0) ? Whf : (g == 1) ? Whi : (g == 2) ? Whg : Who;
      WhT[r] = f2bf(W[k * 512 + hc]);
    } else if (i < NWX + NWH + 2048) {
      int n = (int)(i - NWX - NWH);
      int g = n >> 9, hc = n & 511;
      const float* bi = (g == 0) ? bif : (g == 1) ? bii : (g == 2) ? big : bio;
      const float* bh = (g == 0) ? bhf : (g == 1) ? bhi : (g == 2) ? bhg : bho;
      bias[n] = bi[hc] + bh[hc];
    } else if (i < NWX + NWH + 2048 + NR) {
      long r = i - NWX - NWH - 2048;
      long rr = r & 65535;                     // within-domain index
      hring[r] = (rr < 16384) ? (unsigned short)0 : (unsigned short)0x8000u;
    } else {
      int j = (int)(i - NWX - NWH - 2048 - NR);
      ctrl[j] = (j >= 1 && j <= 64) ? -1 : 0;
    }
  }
}

// ---------------------------------------------------------------------------
// x-projection GEMM: (B*T, 512) @ (512, 2048) + bias -> bf16, written in the
// recurrent kernel's per-lane-packed layout (2-domain, 2x2 wave split):
//   dst = (((t*64 + d*32+wgl)*4 + (mw*2+gw))*64 + (chi*16+lcol))*8 + gs*4+cii
// ---------------------------------------------------------------------------
#define GP 56  // LDS row stride (elems): 112B, 16B-aligned, 2-way banks

__global__ __launch_bounds__(256) void lstm_xproj(
    const float* __restrict__ x, const unsigned short* __restrict__ WxT,
    const float* __restrict__ bias, unsigned short* __restrict__ xp)
{
  __shared__ unsigned short As[128 * GP];
  __shared__ unsigned short Bs[128 * GP];
  int bid = blockIdx.x;
  int mt = bid & 511, nt = bid >> 9;          // 512 m-tiles, 16 n-tiles
  int m0 = mt << 7, n0 = nt << 7;
  int tid = threadIdx.x, lane = tid & 63, w = tid >> 6;
  int wm = w >> 1, wn = w & 1;
  int l15 = lane & 15, hi4 = lane >> 4;

  f32x4 acc[4][4] = {};
  int srow = tid >> 1, skq = (tid & 1) << 4;  // each thread: 1 row, 16 k
  const float* xa = x + (size_t)(m0 + srow) * 512 + skq;
  const unsigned short* bsrc = WxT + (size_t)(n0 + srow) * 512 + skq;
  unsigned short* adst = As + srow * GP + skq;
  unsigned short* bdst = Bs + srow * GP + skq;

  for (int kt = 0; kt < 16; ++kt) {
    f32x4 a0 = *(const f32x4*)(xa + kt * 32);
    f32x4 a1 = *(const f32x4*)(xa + kt * 32 + 4);
    f32x4 a2 = *(const f32x4*)(xa + kt * 32 + 8);
    f32x4 a3 = *(const f32x4*)(xa + kt * 32 + 12);
    u32x4 wv0 = *(const u32x4*)(bsrc + kt * 32);
    u32x4 wv1 = *(const u32x4*)(bsrc + kt * 32 + 8);
    u32x4 p0, p1;
    p0[0] = pk2(a0[0], a0[1]); p0[1] = pk2(a0[2], a0[3]);
    p0[2] = pk2(a1[0], a1[1]); p0[3] = pk2(a1[2], a1[3]);
    p1[0] = pk2(a2[0], a2[1]); p1[1] = pk2(a2[2], a2[3]);
    p1[2] = pk2(a3[0], a3[1]); p1[3] = pk2(a3[2], a3[3]);
    *(u32x4*)adst = p0;  *(u32x4*)(adst + 8) = p1;
    *(u32x4*)bdst = wv0; *(u32x4*)(bdst + 8) = wv1;
    __syncthreads();
    short8 af[4], bfr[4];
    #pragma unroll
    for (int mb = 0; mb < 4; ++mb)
      af[mb] = *(const short8*)(As + (wm * 64 + mb * 16 + l15) * GP + hi4 * 8);
    #pragma unroll
    for (int nb = 0; nb < 4; ++nb)
      bfr[nb] = *(const short8*)(Bs + (wn * 64 + nb * 16 + l15) * GP + hi4 * 8);
    #pragma unroll
    for (int mb = 0; mb < 4; ++mb)
      #pragma unroll
      for (int nb = 0; nb < 4; ++nb)
        acc[mb][nb] = mfma16(af[mb], bfr[nb], acc[mb][nb]);
    __syncthreads();
  }
  // epilogue: +bias, bf16, scatter into packed consumer layout
  #pragma unroll
  for (int nb = 0; nb < 4; ++nb) {
    int n = n0 + wn * 64 + nb * 16 + l15;
    int gate = n >> 9, hc = n & 511, wgc = hc >> 4, lcol = hc & 15;
    int gw2 = gate >> 1, gs2 = gate & 1;
    float bv = bias[n];
    #pragma unroll
    for (int mb = 0; mb < 4; ++mb) {
      int mbase = m0 + wm * 64 + mb * 16 + hi4 * 4;
      #pragma unroll
      for (int i = 0; i < 4; ++i) {
        int m = mbase + i;
        int tt = m & 1023, bb = m >> 10;
        int dd = bb >> 5, rloc = bb & 31;
        int mwc = rloc >> 4, chi = (rloc >> 2) & 3, cii = rloc & 3;
        size_t dst = ((((size_t)tt * 64 + dd * 32 + wgc) * 4 +
                       (mwc * 2 + gw2)) * 64 + (chi * 16 + lcol)) * 8 +
                     gs2 * 4 + cii;
        xp[dst] = f2bf(acc[mb][nb][i] + bv);
      }
    }
  }
}

// ---------------------------------------------------------------------------
// recurrence: 64 worker WGs (2 domains x 32), ALL PINNED TO XCD 0 so the
// h exchange stays in one shared L2. Rank claim via HW_REG_XCC_ID; runtime
// verification (probe match + >=2 distinct xcc among 1024 candidates) gates
// the fast path; any doubt -> safe mode (= R8 protocol, IC-scope loads).
// Stores always sc0 sc1 (write-through past write-back L1 -- R5 lesson).
// Per step: dirty-mask sentinel poll (sc0 fast / sc0 sc1 safe, escalation
// after 8 rounds) -> stage clean granules to swizzled LDS -> re-poison slot
// (t-2)%4 -> B1 -> 32 MFMA/wave -> preact dump -> B2 -> combine -> drain ->
// publish dword.
// ---------------------------------------------------------------------------
#define AWAIT(N) do { \
  asm volatile("s_waitcnt vmcnt(" #N ")" ::: "memory"); \
  __builtin_amdgcn_sched_barrier(0); } while (0)

// L2-scope load (bypass L1 only) -- fast path within one XCD
#define PLD1F(dst, vof, sb) \
  asm volatile("global_load_dwordx4 %0, %1, %2 sc0" \
               : "=v"(dst) : "v"(vof), "s"(sb))
// IC-scope load -- safe path / escalation
#define PLD1E(dst, vof, sb) \
  asm volatile("global_load_dwordx4 %0, %1, %2 sc0 sc1" \
               : "=v"(dst) : "v"(vof), "s"(sb))

// cached dwordx4 load via 64-bit VGPR address (divergence-safe)
#define XLD(dst, a64) \
  asm volatile("global_load_dwordx4 %0, %1, off" : "=v"(dst) : "v"(a64))

__global__ __launch_bounds__(256, 1) void lstm_rec(
    const unsigned short* __restrict__ xp, const unsigned short* __restrict__ WhT,
    unsigned short* __restrict__ hring, int* __restrict__ ctrl,
    float* __restrict__ out)
{
  __shared__ unsigned short hA[16384];   // 32 KB staged h (XOR-swizzled)
  __shared__ float pre[4][32][17];       // 8.7 KB preact exchange
  __shared__ int s_rank;

  int tid = threadIdx.x, lane = tid & 63, w = tid >> 6;
  int mw = w >> 1, gw = w & 1;
  int l15 = lane & 15, hi4 = lane >> 4;

  // ---- candidate report + rank claim (XCD 0 only) ----
  unsigned int xcc;
  asm volatile("s_getreg_b32 %0, hwreg(HW_REG_XCC_ID)" : "=s"(xcc));
  if (tid == 0) {
    atomicOr(&ctrl[65], 1 << (xcc & 31));
    atomicAdd(&ctrl[66], 1);
    int r = -1;
    if (xcc == 0) {
      r = atomicAdd(&ctrl[0], 1);
      if (r >= 64) r = -1;
    }
    s_rank = r;
  }
  __syncthreads();
  int rank = s_rank;
  if (rank < 0) return;                  // not a worker
  int d = rank >> 5, wgl = rank & 31;

  // ---- runtime locality verification -> fast flag ----
  if (tid == 0)
    __hip_atomic_store(&ctrl[1 + rank], (int)xcc, __ATOMIC_RELAXED,
                       __HIP_MEMORY_SCOPE_AGENT);
  int fast;
  {
    unsigned int pv = 0xFFFFFFFFu;
    int spins = 0;
    for (;;) {                           // all 64 probes set?
      pv = (unsigned int)__hip_atomic_load(&ctrl[1 + lane], __ATOMIC_RELAXED,
                                           __HIP_MEMORY_SCOPE_AGENT);
      if (__all((int)(pv != 0xFFFFFFFFu))) break;
      if (++spins > (1 << 17)) break;
    }
    int same = __all((int)(pv == xcc));
    int het = 0;
    spins = 0;
    for (;;) {                           // all 1024 candidates reported?
      int cnt = __hip_atomic_load(&ctrl[66], __ATOMIC_RELAXED,
                                  __HIP_MEMORY_SCOPE_AGENT);
      if (cnt >= 1024) {
        unsigned int msk = (unsigned int)__hip_atomic_load(
            &ctrl[65], __ATOMIC_RELAXED, __HIP_MEMORY_SCOPE_AGENT);
        het = (__popc(msk) >= 2);
        break;
      }
      if (++spins > (1 << 17)) break;
    }
    fast = same && het;                  // uniform across the WG
  }

  // Wh fragments for this wave's 2 gates: 2 x 16 x short8 = 128 VGPR
  short8 bw[2][16];
  #pragma unroll
  for (int gs = 0; gs < 2; ++gs) {
    const unsigned short* wsrc =
        WhT + ((size_t)wgl * 64 + (gw * 2 + gs) * 16 + l15) * 512 + hi4 * 8;
    #pragma unroll
    for (int kk = 0; kk < 16; ++kk)
      bw[gs][kk] = *(const short8*)(wsrc + kk * 32);
  }

  // poll voffsets + swizzled LDS byte for this thread's 8 granules
  unsigned int voff[8], lbyt[8];
  #pragma unroll
  for (int k = 0; k < 8; ++k) {
    int gid = k * 256 + tid;
    int byt = gid * 16;
    int row = gid >> 6;
    voff[k] = (unsigned)byt;
    lbyt[k] = (unsigned)(byt ^ ((row & 7) << 4));
  }

  // gate-combine coordinates: 1 row x 2 consecutive local cols
  const int r = tid >> 3;
  const int cq = (tid & 7) * 2;
  float cst[2] = {0.f, 0.f};
  unsigned int vpub = (unsigned)(r * 1024 + wgl * 32 + cq * 2);

  // per-lane 64-bit xp address (this wave's 16B/lane packet for step t)
  unsigned long long xaddr = (unsigned long long)(uintptr_t)(
      xp + ((size_t)(rank * 4 + w) * 64 + lane) * 8);

  u32x4 pc0, pn0;
  XLD(pc0, xaddr);

  const size_t dring = (size_t)d * 65536;    // domain base (elems)

  for (int t = 0; t < 1024; ++t) {
    const unsigned short* hb = hring + dring + ((size_t)(t & 3) << 14);
    // ---- dirty-mask sentinel poll + incremental staging ----
    u32x4 gb[8];
    {
      unsigned m = 0xFFu;
      int spins = 0;
      if (fast) {
        PLD1F(gb[0], voff[0], hb); PLD1F(gb[1], voff[1], hb);
        PLD1F(gb[2], voff[2], hb); PLD1F(gb[3], voff[3], hb);
        PLD1F(gb[4], voff[4], hb); PLD1F(gb[5], voff[5], hb);
        PLD1F(gb[6], voff[6], hb); PLD1F(gb[7], voff[7], hb);
      } else {
        PLD1E(gb[0], voff[0], hb); PLD1E(gb[1], voff[1], hb);
        PLD1E(gb[2], voff[2], hb); PLD1E(gb[3], voff[3], hb);
        PLD1E(gb[4], voff[4], hb); PLD1E(gb[5], voff[5], hb);
        PLD1E(gb[6], voff[6], hb); PLD1E(gb[7], voff[7], hb);
      }
      for (;;) {
        AWAIT(0);
        unsigned nm = 0;
        #pragma unroll
        for (int k = 0; k < 8; ++k) {
          if ((m >> k) & 1u) {
            u32x4 v = gb[k];
            bool clean = (v[0] != 0x80008000u) && (v[1] != 0x80008000u) &&
                         (v[2] != 0x80008000u) && (v[3] != 0x80008000u);
            if (clean)
              *(u32x4*)((char*)hA + lbyt[k]) = v;   // stage now
            else
              nm |= (1u << k);
          }
        }
        m = nm;
        if (m == 0u) break;
        if (++spins > (1 << 15)) break;   // bounded: fail visibly, never hang
        bool esc = (!fast) || (spins > 8);
        #pragma unroll
        for (int k = 0; k < 8; ++k)
          if ((m >> k) & 1u) {
            if (esc) { PLD1E(gb[k], voff[k], hb); }
            else     { PLD1F(gb[k], voff[k], hb); }
          }
      }
    }
    // ---- re-poison slot (t-2)%4 (own slice; drained before publish) ----
    if (t >= 2) {
      const unsigned short* hp = hring + dring + ((size_t)((t - 2) & 3) << 14);
      unsigned int pv = 0x80008000u;
      asm volatile("global_store_dword %0, %1, %2 sc0 sc1"
                   :: "v"(vpub), "v"(pv), "s"(hp) : "memory");
    }
    __syncthreads();                // B1: staged h_t complete in LDS

    // ---- acc init from prefetched xp ----
    f32x4 acc[2];
    #pragma unroll
    for (int gs = 0; gs < 2; ++gs)
      #pragma unroll
      for (int i = 0; i < 4; ++i) {
        int j = gs * 4 + i;
        unsigned int dw = pc0[j >> 1];
        unsigned short us = (j & 1) ? (unsigned short)(dw >> 16)
                                    : (unsigned short)(dw & 0xFFFFu);
        acc[gs][i] = bf2f(us);
      }
    // prefetch next step's xp
    if (t < 1023) xaddr += 262144ULL;
    XLD(pn0, xaddr);

    // ---- MFMA: a-frags from swizzled LDS, b-frags from regs ----
    #pragma unroll
    for (int kk = 0; kk < 16; ++kk) {
      int r0 = mw * 16 + l15;
      int b0 = (r0 * 1024 + kk * 64 + hi4 * 16) ^ ((r0 & 7) << 4);
      short8 a0 = *(const short8*)((const char*)hA + b0);
      acc[0] = mfma16(a0, bw[0][kk], acc[0]);
      acc[1] = mfma16(a0, bw[1][kk], acc[1]);
    }

    // ---- preact dump ----
    #pragma unroll
    for (int gs = 0; gs < 2; ++gs)
      #pragma unroll
      for (int i = 0; i < 4; ++i)
        pre[gw * 2 + gs][mw * 16 + hi4 * 4 + i][l15] = acc[gs][i];
    __syncthreads();                // B2

    // ---- combine: row r, local cols cq..cq+1 ----
    float hv[2];
    #pragma unroll
    for (int i = 0; i < 2; ++i) {
      float fg = sigm(pre[0][r][cq + i]);
      float ig = sigm(pre[1][r][cq + i]);
      float gg = tanh_(pre[2][r][cq + i]);
      float og = sigm(pre[3][r][cq + i]);
      float c = fg * cst[i] + ig * gg;
      cst[i] = c;
      hv[i] = og * tanh_(c);
    }
    if (t < 1023) {
      AWAIT(0);                     // drain re-poison (+pn prefetch)
      const unsigned short* hbn =
          hring + dring + ((size_t)((t + 1) & 3) << 14);
      unsigned int u0 = f2bf(hv[0]), u1 = f2bf(hv[1]);
      if (u0 == 0x8000u) u0 = 0;    // cleanse -0.0 (poison)
      if (u1 == 0x8000u) u1 = 0;
      unsigned int pk = u0 | (u1 << 16);
      asm volatile("global_store_dword %0, %1, %2 sc0 sc1"
                   :: "v"(vpub), "v"(pk), "s"(hbn) : "memory");
    } else {
      int b = d * 32 + r, col = wgl * 16 + cq;
      out[(size_t)b * 512 + col] = hv[0];
      out[(size_t)b * 512 + col + 1] = hv[1];
      out[32768 + (size_t)b * 512 + col] = cst[0];
      out[32768 + (size_t)b * 512 + col + 1] = cst[1];
    }
    pc0 = pn0;
  }
}

// ---------------------------------------------------------------------------
extern "C" void kernel_launch(void* const* d_in, const int* in_sizes, int n_in,
                              void* d_out, int out_size, void* d_ws, size_t ws_size,
                              hipStream_t stream) {
  const float* x   = (const float*)d_in[0];
  const float* Wii = (const float*)d_in[1];
  const float* Whi = (const float*)d_in[2];
  const float* Wif = (const float*)d_in[3];
  const float* Whf = (const float*)d_in[4];
  const float* Wig = (const float*)d_in[5];
  const float* Whg = (const float*)d_in[6];
  const float* Wio = (const float*)d_in[7];
  const float* Who = (const float*)d_in[8];
  const float* bii = (const float*)d_in[9];
  const float* bhi = (const float*)d_in[10];
  const float* bif = (const float*)d_in[11];
  const float* bhf = (const float*)d_in[12];
  const float* big = (const float*)d_in[13];
  const float* bhg = (const float*)d_in[14];
  const float* bio = (const float*)d_in[15];
  const float* bho = (const float*)d_in[16];

  char* ws = (char*)d_ws;
  size_t off = 0;
  auto alloc = [&](size_t bytes) {
    size_t p = off; off = (off + bytes + 255) & ~(size_t)255; return p;
  };
  unsigned short* WxT  = (unsigned short*)(ws + alloc(2048UL * 512 * 2));
  unsigned short* WhT  = (unsigned short*)(ws + alloc(32UL * 64 * 512 * 2));
  float*          bias = (float*)        (ws + alloc(2048UL * 4));
  unsigned short* hring= (unsigned short*)(ws + alloc(2UL * 4 * 32 * 512 * 2));
  int*            ctrl = (int*)          (ws + alloc(67UL * 4));
  unsigned short* xpb  = (unsigned short*)(ws + alloc(1024UL * 64 * 2048 * 2));
  if (off > ws_size) return;  // insufficient workspace -> fail visibly

  lstm_prep<<<2048, 256, 0, stream>>>(Wif, Wii, Wig, Wio, Whf, Whi, Whg, Who,
                                      bif, bhf, bii, bhi, big, bhg, bio, bho,
                                      WxT, WhT, bias, hring, ctrl);
  lstm_xproj<<<8192, 256, 0, stream>>>(x, WxT, bias, xpb);
  lstm_rec<<<1024, 256, 0, stream>>>(xpb, WhT, hring, ctrl, (float*)d_out);
}

// Round 10
// 5738.060 us; speedup vs baseline: 4.9594x; 4.9594x over previous
//
#include <hip/hip_runtime.h>
#include <hip/hip_bf16.h>
#include <stdint.h>

typedef __attribute__((ext_vector_type(8))) short short8;
typedef __attribute__((ext_vector_type(4))) float f32x4;
typedef __attribute__((ext_vector_type(4))) unsigned int u32x4;

__device__ __forceinline__ unsigned short f2bf(float x) {
  unsigned int u = __builtin_bit_cast(unsigned int, x);
  u += 0x7FFFu + ((u >> 16) & 1u);           // round-to-nearest-even
  return (unsigned short)(u >> 16);
}
__device__ __forceinline__ float bf2f(unsigned short u) {
  unsigned int v = ((unsigned int)u) << 16;
  return __builtin_bit_cast(float, v);
}
__device__ __forceinline__ unsigned int pk2(float a, float b) {
  return (unsigned int)f2bf(a) | ((unsigned int)f2bf(b) << 16);
}
__device__ __forceinline__ float sigm(float x) {
  return __builtin_amdgcn_rcpf(1.0f + __builtin_amdgcn_exp2f(-1.44269504f * x));
}
__device__ __forceinline__ float tanh_(float x) {
  return 2.0f * __builtin_amdgcn_rcpf(1.0f + __builtin_amdgcn_exp2f(-2.88539008f * x)) - 1.0f;
}
__device__ __forceinline__ f32x4 mfma16(short8 a, short8 b, f32x4 c) {
  return __builtin_amdgcn_mfma_f32_16x16x32_bf16(a, b, c, 0, 0, 0);
}
__device__ __forceinline__ short8 bc(u32x4 v) { return __builtin_bit_cast(short8, v); }

// ---------------------------------------------------------------------------
// prep: bf16 transposed weight images, fused bias, init 2-domain h ring.
// Gate order: 0=f, 1=i, 2=g, 3=o.
// WxT: [2048 n][512 k]   WhT: [32 wgl][64 j][512 k]  (j = gate*16 + hc_local)
// h ring: 2 domains x 4 slots x [32 rows][512 cols] bf16.
// Per domain: slot 0 = h_0 = +0.0 (fresh); slots 1..3 = 0x8000 poison
// (bf16 -0.0, never produced: producers cleanse -0.0 -> +0.0).
// ---------------------------------------------------------------------------
__global__ void lstm_prep(
    const float* __restrict__ Wif, const float* __restrict__ Wii,
    const float* __restrict__ Wig, const float* __restrict__ Wio,
    const float* __restrict__ Whf, const float* __restrict__ Whi,
    const float* __restrict__ Whg, const float* __restrict__ Who,
    const float* __restrict__ bif, const float* __restrict__ bhf,
    const float* __restrict__ bii, const float* __restrict__ bhi,
    const float* __restrict__ big, const float* __restrict__ bhg,
    const float* __restrict__ bio, const float* __restrict__ bho,
    unsigned short* __restrict__ WxT, unsigned short* __restrict__ WhT,
    float* __restrict__ bias, unsigned short* __restrict__ hring)
{
  const long NWX = 2048L * 512, NWH = 32L * 64 * 512;
  const long NR = 2L * 4 * 32 * 512;           // ring: 131072 ushorts
  long total = NWX + NWH + 2048 + NR;
  for (long i = (long)blockIdx.x * blockDim.x + threadIdx.x; i < total;
       i += (long)gridDim.x * blockDim.x) {
    if (i < NWX) {
      int n = (int)(i >> 9), k = (int)(i & 511);
      int g = n >> 9, hc = n & 511;
      const float* W = (g == 0) ? Wif : (g == 1) ? Wii : (g == 2) ? Wig : Wio;
      WxT[i] = f2bf(W[k * 512 + hc]);
    } else if (i < NWX + NWH) {
      long r = i - NWX;
      int wg = (int)(r >> 15); int rest = (int)(r & 32767);
      int j = rest >> 9, k = rest & 511;
      int g = j >> 4, hc = wg * 16 + (j & 15);
      const float* W = (g == 0) ? Whf : (g == 1) ? Whi : (g == 2) ? Whg : Who;
      WhT[r] = f2bf(W[k * 512 + hc]);
    } else if (i < NWX + NWH + 2048) {
      int n = (int)(i - NWX - NWH);
      int g = n >> 9, hc = n & 511;
      const float* bi = (g == 0) ? bif : (g == 1) ? bii : (g == 2) ? big : bio;
      const float* bh = (g == 0) ? bhf : (g == 1) ? bhi : (g == 2) ? bhg : bho;
      bias[n] = bi[hc] + bh[hc];
    } else {
      long r = i - NWX - NWH - 2048;
      long rr = r & 65535;                     // within-domain index
      hring[r] = (rr < 16384) ? (unsigned short)0 : (unsigned short)0x8000u;
    }
  }
}

// ---------------------------------------------------------------------------
// x-projection GEMM: (B*T, 512) @ (512, 2048) + bias -> bf16, written in the
// recurrent kernel's per-lane-packed layout (2-domain, 2x2 wave split):
//   dst = (((t*64 + d*32+wgl)*4 + (mw*2+gw))*64 + (chi*16+lcol))*8 + gs*4+cii
// ---------------------------------------------------------------------------
#define GP 56  // LDS row stride (elems): 112B, 16B-aligned, 2-way banks

__global__ __launch_bounds__(256) void lstm_xproj(
    const float* __restrict__ x, const unsigned short* __restrict__ WxT,
    const float* __restrict__ bias, unsigned short* __restrict__ xp)
{
  __shared__ unsigned short As[128 * GP];
  __shared__ unsigned short Bs[128 * GP];
  int bid = blockIdx.x;
  int mt = bid & 511, nt = bid >> 9;          // 512 m-tiles, 16 n-tiles
  int m0 = mt << 7, n0 = nt << 7;
  int tid = threadIdx.x, lane = tid & 63, w = tid >> 6;
  int wm = w >> 1, wn = w & 1;
  int l15 = lane & 15, hi4 = lane >> 4;

  f32x4 acc[4][4] = {};
  int srow = tid >> 1, skq = (tid & 1) << 4;  // each thread: 1 row, 16 k
  const float* xa = x + (size_t)(m0 + srow) * 512 + skq;
  const unsigned short* bsrc = WxT + (size_t)(n0 + srow) * 512 + skq;
  unsigned short* adst = As + srow * GP + skq;
  unsigned short* bdst = Bs + srow * GP + skq;

  for (int kt = 0; kt < 16; ++kt) {
    f32x4 a0 = *(const f32x4*)(xa + kt * 32);
    f32x4 a1 = *(const f32x4*)(xa + kt * 32 + 4);
    f32x4 a2 = *(const f32x4*)(xa + kt * 32 + 8);
    f32x4 a3 = *(const f32x4*)(xa + kt * 32 + 12);
    u32x4 wv0 = *(const u32x4*)(bsrc + kt * 32);
    u32x4 wv1 = *(const u32x4*)(bsrc + kt * 32 + 8);
    u32x4 p0, p1;
    p0[0] = pk2(a0[0], a0[1]); p0[1] = pk2(a0[2], a0[3]);
    p0[2] = pk2(a1[0], a1[1]); p0[3] = pk2(a1[2], a1[3]);
    p1[0] = pk2(a2[0], a2[1]); p1[1] = pk2(a2[2], a2[3]);
    p1[2] = pk2(a3[0], a3[1]); p1[3] = pk2(a3[2], a3[3]);
    *(u32x4*)adst = p0;  *(u32x4*)(adst + 8) = p1;
    *(u32x4*)bdst = wv0; *(u32x4*)(bdst + 8) = wv1;
    __syncthreads();
    short8 af[4], bfr[4];
    #pragma unroll
    for (int mb = 0; mb < 4; ++mb)
      af[mb] = *(const short8*)(As + (wm * 64 + mb * 16 + l15) * GP + hi4 * 8);
    #pragma unroll
    for (int nb = 0; nb < 4; ++nb)
      bfr[nb] = *(const short8*)(Bs + (wn * 64 + nb * 16 + l15) * GP + hi4 * 8);
    #pragma unroll
    for (int mb = 0; mb < 4; ++mb)
      #pragma unroll
      for (int nb = 0; nb < 4; ++nb)
        acc[mb][nb] = mfma16(af[mb], bfr[nb], acc[mb][nb]);
    __syncthreads();
  }
  // epilogue: +bias, bf16, scatter into packed consumer layout
  #pragma unroll
  for (int nb = 0; nb < 4; ++nb) {
    int n = n0 + wn * 64 + nb * 16 + l15;
    int gate = n >> 9, hc = n & 511, wgc = hc >> 4, lcol = hc & 15;
    int gw2 = gate >> 1, gs2 = gate & 1;
    float bv = bias[n];
    #pragma unroll
    for (int mb = 0; mb < 4; ++mb) {
      int mbase = m0 + wm * 64 + mb * 16 + hi4 * 4;
      #pragma unroll
      for (int i = 0; i < 4; ++i) {
        int m = mbase + i;
        int tt = m & 1023, bb = m >> 10;
        int dd = bb >> 5, rloc = bb & 31;
        int mwc = rloc >> 4, chi = (rloc >> 2) & 3, cii = rloc & 3;
        size_t dst = ((((size_t)tt * 64 + dd * 32 + wgc) * 4 +
                       (mwc * 2 + gw2)) * 64 + (chi * 16 + lcol)) * 8 +
                     gs2 * 4 + cii;
        xp[dst] = f2bf(acc[mb][nb][i] + bv);
      }
    }
  }
}

// ---------------------------------------------------------------------------
// recurrence: 32 WGs, each owning h-cols [wgl*16,+16) of BOTH 32-row batch
// domains, processed as 2 phases/step. Domain d's h(t+1) is published in
// phase d of step t and consumed a FULL STEP later (phase d of t+1), with
// first-round poll loads issued one phase early -> the IC round trip hides
// under the other domain's staging+MFMA. Protocol identical to R8
// (sentinel ring, sc0 sc1, dirty-mask incremental staging, re-poison t-2).
// ---------------------------------------------------------------------------
#define AWAIT(N) do { \
  asm volatile("s_waitcnt vmcnt(" #N ")" ::: "memory"); \
  __builtin_amdgcn_sched_barrier(0); } while (0)

#define PLD1(dst, vof, sb) \
  asm volatile("global_load_dwordx4 %0, %1, %2 sc0 sc1" \
               : "=v"(dst) : "v"(vof), "s"(sb))

#define XLD(dst, a64) \
  asm volatile("global_load_dwordx4 %0, %1, off" : "=v"(dst) : "v"(a64))

__global__ __launch_bounds__(256, 1) void lstm_rec(
    const unsigned short* __restrict__ xp, const unsigned short* __restrict__ WhT,
    unsigned short* __restrict__ hring, float* __restrict__ out)
{
  __shared__ unsigned short hA[16384];   // 32 KB staged h (XOR-swizzled)
  __shared__ float pre[4][32][17];       // 8.7 KB preact exchange

  int wgl = blockIdx.x;
  int tid = threadIdx.x, lane = tid & 63, w = tid >> 6;
  int mw = w >> 1, gw = w & 1;
  int l15 = lane & 15, hi4 = lane >> 4;

  // Wh fragments for this wave's 2 gates (domain-independent): 128 VGPR
  short8 bw[2][16];
  #pragma unroll
  for (int gs = 0; gs < 2; ++gs) {
    const unsigned short* wsrc =
        WhT + ((size_t)wgl * 64 + (gw * 2 + gs) * 16 + l15) * 512 + hi4 * 8;
    #pragma unroll
    for (int kk = 0; kk < 16; ++kk)
      bw[gs][kk] = *(const short8*)(wsrc + kk * 32);
  }

  // poll voffsets + swizzled LDS byte for this thread's 8 granules
  unsigned int voff[8], lbyt[8];
  #pragma unroll
  for (int k = 0; k < 8; ++k) {
    int gid = k * 256 + tid;
    int byt = gid * 16;
    int row = gid >> 6;
    voff[k] = (unsigned)byt;
    lbyt[k] = (unsigned)(byt ^ ((row & 7) << 4));
  }

  // gate-combine coordinates: 1 row x 2 consecutive local cols
  const int r = tid >> 3;
  const int cq = (tid & 7) * 2;
  float cst0[2] = {0.f, 0.f}, cst1[2] = {0.f, 0.f};
  unsigned int vpub = (unsigned)(r * 1024 + wgl * 32 + cq * 2);

  // per-lane 64-bit xp addresses for the two domains' packets
  unsigned long long xaddr0 = (unsigned long long)(uintptr_t)(
      xp + ((size_t)(wgl * 4 + w) * 64 + lane) * 8);
  unsigned long long xaddr1 = (unsigned long long)(uintptr_t)(
      xp + ((size_t)((32 + wgl) * 4 + w) * 64 + lane) * 8);

  u32x4 pcA, pnA, pcB, pnB;
  XLD(pcA, xaddr0);
  XLD(pcB, xaddr1);

  u32x4 gbA[8], gbB[8];
  // prologue: first-round poll loads for domain 0, t=0 (slot 0 is fresh)
  {
    const unsigned short* hb0 = hring;                 // d0 base, slot 0
    #pragma unroll
    for (int k = 0; k < 8; ++k) PLD1(gbA[k], voff[k], hb0);
  }

  for (int t = 0; t < 1024; ++t) {
    // =================== PHASE A: domain 0 (rows 0..31) ===================
    const unsigned short* hbA = hring + ((size_t)(t & 3) << 14);
    {
      unsigned m = 0xFFu;
      int spins = 0;
      for (;;) {
        AWAIT(0);
        unsigned nm = 0;
        #pragma unroll
        for (int k = 0; k < 8; ++k) {
          if ((m >> k) & 1u) {
            u32x4 v = gbA[k];
            bool clean = (v[0] != 0x80008000u) && (v[1] != 0x80008000u) &&
                         (v[2] != 0x80008000u) && (v[3] != 0x80008000u);
            if (clean)
              *(u32x4*)((char*)hA + lbyt[k]) = v;
            else
              nm |= (1u << k);
          }
        }
        m = nm;
        if (m == 0u) break;
        if (++spins > (1 << 15)) break;   // bounded: fail visibly, never hang
        #pragma unroll
        for (int k = 0; k < 8; ++k)
          if ((m >> k) & 1u) PLD1(gbA[k], voff[k], hbA);
      }
    }
    if (t >= 2) {   // re-poison d0 slot (t-2)%4 (own slice; safe, see header)
      const unsigned short* hp = hring + ((size_t)((t - 2) & 3) << 14);
      unsigned int pv = 0x80008000u;
      asm volatile("global_store_dword %0, %1, %2 sc0 sc1"
                   :: "v"(vpub), "v"(pv), "s"(hp) : "memory");
    }
    // early issue: first-round poll loads for domain 1, step t
    {
      const unsigned short* hbB = hring + 65536 + ((size_t)(t & 3) << 14);
      #pragma unroll
      for (int k = 0; k < 8; ++k) PLD1(gbB[k], voff[k], hbB);
    }
    __syncthreads();                // B1: staged d0 h_t complete in LDS

    f32x4 acc[2];
    #pragma unroll
    for (int gs = 0; gs < 2; ++gs)
      #pragma unroll
      for (int i = 0; i < 4; ++i) {
        int j = gs * 4 + i;
        unsigned int dw = pcA[j >> 1];
        unsigned short us = (j & 1) ? (unsigned short)(dw >> 16)
                                    : (unsigned short)(dw & 0xFFFFu);
        acc[gs][i] = bf2f(us);
      }
    if (t < 1023) xaddr0 += 262144ULL;
    XLD(pnA, xaddr0);

    #pragma unroll
    for (int kk = 0; kk < 16; ++kk) {
      int r0 = mw * 16 + l15;
      int b0 = (r0 * 1024 + kk * 64 + hi4 * 16) ^ ((r0 & 7) << 4);
      short8 a0 = *(const short8*)((const char*)hA + b0);
      acc[0] = mfma16(a0, bw[0][kk], acc[0]);
      acc[1] = mfma16(a0, bw[1][kk], acc[1]);
    }
    #pragma unroll
    for (int gs = 0; gs < 2; ++gs)
      #pragma unroll
      for (int i = 0; i < 4; ++i)
        pre[gw * 2 + gs][mw * 16 + hi4 * 4 + i][l15] = acc[gs][i];
    __syncthreads();                // B2

    {
      float hv[2];
      #pragma unroll
      for (int i = 0; i < 2; ++i) {
        float fg = sigm(pre[0][r][cq + i]);
        float ig = sigm(pre[1][r][cq + i]);
        float gg = tanh_(pre[2][r][cq + i]);
        float og = sigm(pre[3][r][cq + i]);
        float c = fg * cst0[i] + ig * gg;
        cst0[i] = c;
        hv[i] = og * tanh_(c);
      }
      if (t < 1023) {
        AWAIT(0);                   // drain re-poison (gbB also old by now)
        const unsigned short* hbn = hring + ((size_t)((t + 1) & 3) << 14);
        unsigned int u0 = f2bf(hv[0]), u1 = f2bf(hv[1]);
        if (u0 == 0x8000u) u0 = 0;
        if (u1 == 0x8000u) u1 = 0;
        unsigned int pk = u0 | (u1 << 16);
        asm volatile("global_store_dword %0, %1, %2 sc0 sc1"
                     :: "v"(vpub), "v"(pk), "s"(hbn) : "memory");
      } else {
        int b = r, col = wgl * 16 + cq;
        out[(size_t)b * 512 + col] = hv[0];
        out[(size_t)b * 512 + col + 1] = hv[1];
        out[32768 + (size_t)b * 512 + col] = cst0[0];
        out[32768 + (size_t)b * 512 + col + 1] = cst0[1];
      }
    }
    pcA = pnA;

    // =================== PHASE B: domain 1 (rows 32..63) ==================
    const unsigned short* hbB = hring + 65536 + ((size_t)(t & 3) << 14);
    {
      unsigned m = 0xFFu;
      int spins = 0;
      for (;;) {
        AWAIT(0);
        unsigned nm = 0;
        #pragma unroll
        for (int k = 0; k < 8; ++k) {
          if ((m >> k) & 1u) {
            u32x4 v = gbB[k];
            bool clean = (v[0] != 0x80008000u) && (v[1] != 0x80008000u) &&
                         (v[2] != 0x80008000u) && (v[3] != 0x80008000u);
            if (clean)
              *(u32x4*)((char*)hA + lbyt[k]) = v;
            else
              nm |= (1u << k);
          }
        }
        m = nm;
        if (m == 0u) break;
        if (++spins > (1 << 15)) break;
        #pragma unroll
        for (int k = 0; k < 8; ++k)
          if ((m >> k) & 1u) PLD1(gbB[k], voff[k], hbB);
      }
    }
    if (t >= 2) {   // re-poison d1 slot (t-2)%4
      const unsigned short* hp =
          hring + 65536 + ((size_t)((t - 2) & 3) << 14);
      unsigned int pv = 0x80008000u;
      asm volatile("global_store_dword %0, %1, %2 sc0 sc1"
                   :: "v"(vpub), "v"(pv), "s"(hp) : "memory");
    }
    // early issue: first-round poll loads for domain 0, step t+1
    if (t < 1023) {
      const unsigned short* hbn0 = hring + ((size_t)((t + 1) & 3) << 14);
      #pragma unroll
      for (int k = 0; k < 8; ++k) PLD1(gbA[k], voff[k], hbn0);
    }
    __syncthreads();                // B1'

    #pragma unroll
    for (int gs = 0; gs < 2; ++gs)
      #pragma unroll
      for (int i = 0; i < 4; ++i) {
        int j = gs * 4 + i;
        unsigned int dw = pcB[j >> 1];
        unsigned short us = (j & 1) ? (unsigned short)(dw >> 16)
                                    : (unsigned short)(dw & 0xFFFFu);
        acc[gs][i] = bf2f(us);
      }
    if (t < 1023) xaddr1 += 262144ULL;
    XLD(pnB, xaddr1);

    #pragma unroll
    for (int kk = 0; kk < 16; ++kk) {
      int r0 = mw * 16 + l15;
      int b0 = (r0 * 1024 + kk * 64 + hi4 * 16) ^ ((r0 & 7) << 4);
      short8 a0 = *(const short8*)((const char*)hA + b0);
      acc[0] = mfma16(a0, bw[0][kk], acc[0]);
      acc[1] = mfma16(a0, bw[1][kk], acc[1]);
    }
    #pragma unroll
    for (int gs = 0; gs < 2; ++gs)
      #pragma unroll
      for (int i = 0; i < 4; ++i)
        pre[gw * 2 + gs][mw * 16 + hi4 * 4 + i][l15] = acc[gs][i];
    __syncthreads();                // B2'

    {
      float hv[2];
      #pragma unroll
      for (int i = 0; i < 2; ++i) {
        float fg = sigm(pre[0][r][cq + i]);
        float ig = sigm(pre[1][r][cq + i]);
        float gg = tanh_(pre[2][r][cq + i]);
        float og = sigm(pre[3][r][cq + i]);
        float c = fg * cst1[i] + ig * gg;
        cst1[i] = c;
        hv[i] = og * tanh_(c);
      }
      if (t < 1023) {
        AWAIT(0);                   // drain re-poison (gbA prefetch stays? no:
                                    // waits it too -- it is 1 round old, ok)
        const unsigned short* hbn =
            hring + 65536 + ((size_t)((t + 1) & 3) << 14);
        unsigned int u0 = f2bf(hv[0]), u1 = f2bf(hv[1]);
        if (u0 == 0x8000u) u0 = 0;
        if (u1 == 0x8000u) u1 = 0;
        unsigned int pk = u0 | (u1 << 16);
        asm volatile("global_store_dword %0, %1, %2 sc0 sc1"
                     :: "v"(vpub), "v"(pk), "s"(hbn) : "memory");
      } else {
        int b = 32 + r, col = wgl * 16 + cq;
        out[(size_t)b * 512 + col] = hv[0];
        out[(size_t)b * 512 + col + 1] = hv[1];
        out[32768 + (size_t)b * 512 + col] = cst1[0];
        out[32768 + (size_t)b * 512 + col + 1] = cst1[1];
      }
    }
    pcB = pnB;
  }
}

// ---------------------------------------------------------------------------
extern "C" void kernel_launch(void* const* d_in, const int* in_sizes, int n_in,
                              void* d_out, int out_size, void* d_ws, size_t ws_size,
                              hipStream_t stream) {
  const float* x   = (const float*)d_in[0];
  const float* Wii = (const float*)d_in[1];
  const float* Whi = (const float*)d_in[2];
  const float* Wif = (const float*)d_in[3];
  const float* Whf = (const float*)d_in[4];
  const float* Wig = (const float*)d_in[5];
  const float* Whg = (const float*)d_in[6];
  const float* Wio = (const float*)d_in[7];
  const float* Who = (const float*)d_in[8];
  const float* bii = (const float*)d_in[9];
  const float* bhi = (const float*)d_in[10];
  const float* bif = (const float*)d_in[11];
  const float* bhf = (const float*)d_in[12];
  const float* big = (const float*)d_in[13];
  const float* bhg = (const float*)d_in[14];
  const float* bio = (const float*)d_in[15];
  const float* bho = (const float*)d_in[16];

  char* ws = (char*)d_ws;
  size_t off = 0;
  auto alloc = [&](size_t bytes) {
    size_t p = off; off = (off + bytes + 255) & ~(size_t)255; return p;
  };
  unsigned short* WxT  = (unsigned short*)(ws + alloc(2048UL * 512 * 2));
  unsigned short* WhT  = (unsigned short*)(ws + alloc(32UL * 64 * 512 * 2));
  float*          bias = (float*)        (ws + alloc(2048UL * 4));
  unsigned short* hring= (unsigned short*)(ws + alloc(2UL * 4 * 32 * 512 * 2));
  unsigned short* xpb  = (unsigned short*)(ws + alloc(1024UL * 64 * 2048 * 2));
  if (off > ws_size) return;  // insufficient workspace -> fail visibly

  lstm_prep<<<2048, 256, 0, stream>>>(Wif, Wii, Wig, Wio, Whf, Whi, Whg, Who,
                                      bif, bhf, bii, bhi, big, bhg, bio, bho,
                                      WxT, WhT, bias, hring);
  lstm_xproj<<<8192, 256, 0, stream>>>(x, WxT, bias, xpb);
  lstm_rec<<<32, 256, 0, stream>>>(xpb, WhT, hring, (float*)d_out);
}

// Round 11
// 2653.218 us; speedup vs baseline: 10.7256x; 2.1627x over previous
//
#include <hip/hip_runtime.h>
#include <hip/hip_bf16.h>
#include <stdint.h>

typedef __attribute__((ext_vector_type(8))) short short8;
typedef __attribute__((ext_vector_type(4))) float f32x4;
typedef __attribute__((ext_vector_type(4))) unsigned int u32x4;
typedef __attribute__((ext_vector_type(2))) unsigned int u32x2;

__device__ __forceinline__ unsigned short f2bf(float x) {
  unsigned int u = __builtin_bit_cast(unsigned int, x);
  u += 0x7FFFu + ((u >> 16) & 1u);           // round-to-nearest-even
  return (unsigned short)(u >> 16);
}
__device__ __forceinline__ float bf2f(unsigned short u) {
  unsigned int v = ((unsigned int)u) << 16;
  return __builtin_bit_cast(float, v);
}
__device__ __forceinline__ unsigned int pk2(float a, float b) {
  return (unsigned int)f2bf(a) | ((unsigned int)f2bf(b) << 16);
}
__device__ __forceinline__ float sigm(float x) {
  return __builtin_amdgcn_rcpf(1.0f + __builtin_amdgcn_exp2f(-1.44269504f * x));
}
__device__ __forceinline__ float tanh_(float x) {
  return 2.0f * __builtin_amdgcn_rcpf(1.0f + __builtin_amdgcn_exp2f(-2.88539008f * x)) - 1.0f;
}
__device__ __forceinline__ f32x4 mfma16(short8 a, short8 b, f32x4 c) {
  return __builtin_amdgcn_mfma_f32_16x16x32_bf16(a, b, c, 0, 0, 0);
}
__device__ __forceinline__ short8 bc(u32x4 v) { return __builtin_bit_cast(short8, v); }

// ---------------------------------------------------------------------------
// prep: bf16 transposed weight images, fused bias, init 4-domain h ring.
// Gate order: 0=f, 1=i, 2=g, 3=o.
// WxT: [2048 n][512 k]   WhT: [32 wgl][64 j][512 k]  (j = gate*16 + hc_local)
// h ring: 4 domains x 4 slots x [16 rows][512 cols] bf16 (domain d = batch
// rows 16d..16d+15). Per domain: slot 0 = h_0 = +0.0 (fresh); slots 1..3 =
// 0x8000 poison (bf16 -0.0, never produced: producers cleanse).
// ---------------------------------------------------------------------------
__global__ void lstm_prep(
    const float* __restrict__ Wif, const float* __restrict__ Wii,
    const float* __restrict__ Wig, const float* __restrict__ Wio,
    const float* __restrict__ Whf, const float* __restrict__ Whi,
    const float* __restrict__ Whg, const float* __restrict__ Who,
    const float* __restrict__ bif, const float* __restrict__ bhf,
    const float* __restrict__ bii, const float* __restrict__ bhi,
    const float* __restrict__ big, const float* __restrict__ bhg,
    const float* __restrict__ bio, const float* __restrict__ bho,
    unsigned short* __restrict__ WxT, unsigned short* __restrict__ WhT,
    float* __restrict__ bias, unsigned short* __restrict__ hring)
{
  const long NWX = 2048L * 512, NWH = 32L * 64 * 512;
  const long NR = 4L * 4 * 16 * 512;           // ring: 131072 ushorts
  long total = NWX + NWH + 2048 + NR;
  for (long i = (long)blockIdx.x * blockDim.x + threadIdx.x; i < total;
       i += (long)gridDim.x * blockDim.x) {
    if (i < NWX) {
      int n = (int)(i >> 9), k = (int)(i & 511);
      int g = n >> 9, hc = n & 511;
      const float* W = (g == 0) ? Wif : (g == 1) ? Wii : (g == 2) ? Wig : Wio;
      WxT[i] = f2bf(W[k * 512 + hc]);
    } else if (i < NWX + NWH) {
      long r = i - NWX;
      int wg = (int)(r >> 15); int rest = (int)(r & 32767);
      int j = rest >> 9, k = rest & 511;
      int g = j >> 4, hc = wg * 16 + (j & 15);
      const float* W = (g == 0) ? Whf : (g == 1) ? Whi : (g == 2) ? Whg : Who;
      WhT[r] = f2bf(W[k * 512 + hc]);
    } else if (i < NWX + NWH + 2048) {
      int n = (int)(i - NWX - NWH);
      int g = n >> 9, hc = n & 511;
      const float* bi = (g == 0) ? bif : (g == 1) ? bii : (g == 2) ? big : bio;
      const float* bh = (g == 0) ? bhf : (g == 1) ? bhi : (g == 2) ? bhg : bho;
      bias[n] = bi[hc] + bh[hc];
    } else {
      long r = i - NWX - NWH - 2048;
      long rr = r & 32767;                     // within-domain index
      hring[r] = (rr < 8192) ? (unsigned short)0 : (unsigned short)0x8000u;
    }
  }
}

// ---------------------------------------------------------------------------
// x-projection GEMM: (B*T, 512) @ (512, 2048) + bias -> bf16, written in the
// recurrent kernel's per-lane-packed layout (4-domain, gate-per-wave):
//   dst = ((((t*128 + dd*32 + wgl)*4 + gate)*64 + (chi*16+lcol))*4 + cii
// where b = dd*16 + rloc, chi = rloc>>2, cii = rloc&3, lcol = hc&15.
// ---------------------------------------------------------------------------
#define GP 56  // LDS row stride (elems): 112B, 16B-aligned, 2-way banks

__global__ __launch_bounds__(256) void lstm_xproj(
    const float* __restrict__ x, const unsigned short* __restrict__ WxT,
    const float* __restrict__ bias, unsigned short* __restrict__ xp)
{
  __shared__ unsigned short As[128 * GP];
  __shared__ unsigned short Bs[128 * GP];
  int bid = blockIdx.x;
  int mt = bid & 511, nt = bid >> 9;          // 512 m-tiles, 16 n-tiles
  int m0 = mt << 7, n0 = nt << 7;
  int tid = threadIdx.x, lane = tid & 63, w = tid >> 6;
  int wm = w >> 1, wn = w & 1;
  int l15 = lane & 15, hi4 = lane >> 4;

  f32x4 acc[4][4] = {};
  int srow = tid >> 1, skq = (tid & 1) << 4;  // each thread: 1 row, 16 k
  const float* xa = x + (size_t)(m0 + srow) * 512 + skq;
  const unsigned short* bsrc = WxT + (size_t)(n0 + srow) * 512 + skq;
  unsigned short* adst = As + srow * GP + skq;
  unsigned short* bdst = Bs + srow * GP + skq;

  for (int kt = 0; kt < 16; ++kt) {
    f32x4 a0 = *(const f32x4*)(xa + kt * 32);
    f32x4 a1 = *(const f32x4*)(xa + kt * 32 + 4);
    f32x4 a2 = *(const f32x4*)(xa + kt * 32 + 8);
    f32x4 a3 = *(const f32x4*)(xa + kt * 32 + 12);
    u32x4 wv0 = *(const u32x4*)(bsrc + kt * 32);
    u32x4 wv1 = *(const u32x4*)(bsrc + kt * 32 + 8);
    u32x4 p0, p1;
    p0[0] = pk2(a0[0], a0[1]); p0[1] = pk2(a0[2], a0[3]);
    p0[2] = pk2(a1[0], a1[1]); p0[3] = pk2(a1[2], a1[3]);
    p1[0] = pk2(a2[0], a2[1]); p1[1] = pk2(a2[2], a2[3]);
    p1[2] = pk2(a3[0], a3[1]); p1[3] = pk2(a3[2], a3[3]);
    *(u32x4*)adst = p0;  *(u32x4*)(adst + 8) = p1;
    *(u32x4*)bdst = wv0; *(u32x4*)(bdst + 8) = wv1;
    __syncthreads();
    short8 af[4], bfr[4];
    #pragma unroll
    for (int mb = 0; mb < 4; ++mb)
      af[mb] = *(const short8*)(As + (wm * 64 + mb * 16 + l15) * GP + hi4 * 8);
    #pragma unroll
    for (int nb = 0; nb < 4; ++nb)
      bfr[nb] = *(const short8*)(Bs + (wn * 64 + nb * 16 + l15) * GP + hi4 * 8);
    #pragma unroll
    for (int mb = 0; mb < 4; ++mb)
      #pragma unroll
      for (int nb = 0; nb < 4; ++nb)
        acc[mb][nb] = mfma16(af[mb], bfr[nb], acc[mb][nb]);
    __syncthreads();
  }
  // epilogue: +bias, bf16, scatter into packed consumer layout
  #pragma unroll
  for (int nb = 0; nb < 4; ++nb) {
    int n = n0 + wn * 64 + nb * 16 + l15;
    int gate = n >> 9, hc = n & 511, wgc = hc >> 4, lcol = hc & 15;
    float bv = bias[n];
    #pragma unroll
    for (int mb = 0; mb < 4; ++mb) {
      int mbase = m0 + wm * 64 + mb * 16 + hi4 * 4;
      #pragma unroll
      for (int i = 0; i < 4; ++i) {
        int m = mbase + i;
        int tt = m & 1023, bb = m >> 10;
        int ddc = bb >> 4, rloc = bb & 15;
        int chi = rloc >> 2, cii = rloc & 3;
        size_t dst = ((((size_t)tt * 128 + ddc * 32 + wgc) * 4 + gate) * 64 +
                      (size_t)(chi * 16 + lcol)) * 4 + cii;
        xp[dst] = f2bf(acc[mb][nb][i] + bv);
      }
    }
  }
}

// ---------------------------------------------------------------------------
// recurrence: 4 independent batch domains x 32 WGs = 128 WGs. WG (dd,wgl)
// owns domain dd's 16 rows x h-cols [wgl*16,+16). Wave g = gate g (Wh slice
// in 64 VGPRs), 16 MFMA/wave/step. R8 protocol with 3 latency fixes:
//  - re-poison issued at TOP of step (drained by the poll's own AWAIT(0)),
//    so the pre-publish vmcnt drain is deleted (publish off critical path);
//  - first-round poll loads for slot t+1 issued right after B2 (RT overlaps
//    combine+publish); safety: by poll@t success all re-poisons of slot t+1
//    (issued at t-1, drained before h_t publish) are committed;
//  - own 16 cols are written to LDS directly from combine regs and excluded
//    from polling (no self-race with the early issue).
// ---------------------------------------------------------------------------
#define AWAIT(N) do { \
  asm volatile("s_waitcnt vmcnt(" #N ")" ::: "memory"); \
  __builtin_amdgcn_sched_barrier(0); } while (0)

#define PLD1(dst, vof, sb) \
  asm volatile("global_load_dwordx4 %0, %1, %2 sc0 sc1" \
               : "=v"(dst) : "v"(vof), "s"(sb))

#define XLD2(dst, a64) \
  asm volatile("global_load_dwordx2 %0, %1, off" : "=v"(dst) : "v"(a64))

__global__ __launch_bounds__(256, 1) void lstm_rec(
    const unsigned short* __restrict__ xp, const unsigned short* __restrict__ WhT,
    unsigned short* __restrict__ hring, float* __restrict__ out)
{
  __shared__ unsigned short hA[8192];    // 16 KB staged h (XOR-swizzled)
  __shared__ float pre[4][16][17];       // 4.4 KB preact exchange

  int wgG = blockIdx.x;
  int dd = wgG >> 5, wgl = wgG & 31;
  int tid = threadIdx.x, lane = tid & 63, g = tid >> 6;   // wave = gate
  int l15 = lane & 15, hi4 = lane >> 4;

  // Wh fragments for this wave's gate: 16 x short8 = 64 VGPR
  short8 bw[16];
  {
    const unsigned short* wsrc =
        WhT + ((size_t)wgl * 64 + g * 16 + l15) * 512 + hi4 * 8;
    #pragma unroll
    for (int kk = 0; kk < 16; ++kk)
      bw[kk] = *(const short8*)(wsrc + kk * 32);
  }

  // poll voffsets + swizzled LDS bytes: 4 granules/thread (16B each)
  unsigned int voff[4], lbyt[4];
  #pragma unroll
  for (int k = 0; k < 4; ++k) {
    int gid = k * 256 + tid;         // granule id 0..1023
    int byt = gid * 16;
    int row = gid >> 6;              // 16 rows, 64 granules/row
    voff[k] = (unsigned)byt;
    lbyt[k] = (unsigned)(byt ^ ((row & 7) << 4));
  }
  // own-column granules (gcol = tid&63, independent of k): excluded from poll
  int gcol = tid & 63;
  unsigned own = (gcol == wgl * 2 || gcol == wgl * 2 + 1) ? 0xFu : 0x0u;

  // combine coords (tid < 128): row r, 2 consecutive local cols
  const int r = (tid & 127) >> 3;
  const int cq = (tid & 7) * 2;
  float cst[2] = {0.f, 0.f};
  unsigned int vpub = (unsigned)(r * 1024 + (wgl * 16 + cq) * 2);
  unsigned int lown = (unsigned)((r * 1024 + (wgl * 16 + cq) * 2)
                                 ^ ((r & 7) << 4));

  // per-lane 64-bit xp address (this wave's 8B/lane packet for step t)
  unsigned long long xaddr = (unsigned long long)(uintptr_t)(
      xp + ((size_t)(wgG * 4 + g) * 64 + lane) * 4);

  u32x2 pc, pn;
  XLD2(pc, xaddr);

  const size_t dbase = (size_t)dd * 32768;   // domain base (elems)

  u32x4 gb[4];
  // prologue: first-round polls for slot 0 (fresh from prep)
  {
    const unsigned short* hb = hring + dbase;
    #pragma unroll
    for (int k = 0; k < 4; ++k) PLD1(gb[k], voff[k], hb);
  }

  for (int t = 0; t < 1024; ++t) {
    const unsigned short* hb = hring + dbase + ((size_t)(t & 3) << 13);
    // ---- re-poison slot (t-2): issued BEFORE the poll drain ----
    if (t >= 2 && tid < 128) {
      const unsigned short* hp = hring + dbase + ((size_t)((t - 2) & 3) << 13);
      unsigned int pv = 0x80008000u;
      asm volatile("global_store_dword %0, %1, %2 sc0 sc1"
                   :: "v"(vpub), "v"(pv), "s"(hp) : "memory");
    }
    // ---- dirty-mask sentinel poll (first-round loads already in flight) ----
    {
      unsigned m = (t == 0) ? 0xFu : (0xFu & ~own);
      int spins = 0;
      for (;;) {
        AWAIT(0);                    // also drains re-poison, pn, publish acks
        unsigned nm = 0;
        #pragma unroll
        for (int k = 0; k < 4; ++k) {
          if ((m >> k) & 1u) {
            u32x4 v = gb[k];
            bool clean = (v[0] != 0x80008000u) && (v[1] != 0x80008000u) &&
                         (v[2] != 0x80008000u) && (v[3] != 0x80008000u);
            if (clean)
              *(u32x4*)((char*)hA + lbyt[k]) = v;   // stage now
            else
              nm |= (1u << k);
          }
        }
        m = nm;
        if (m == 0u) break;
        if (++spins > (1 << 15)) break;   // bounded: fail visibly, never hang
        #pragma unroll
        for (int k = 0; k < 4; ++k)
          if ((m >> k) & 1u) PLD1(gb[k], voff[k], hb);
      }
    }
    __syncthreads();                // B1: staged h_t complete in LDS

    // ---- acc init from prefetched xp ----
    f32x4 acc;
    #pragma unroll
    for (int i = 0; i < 4; ++i) {
      unsigned int dw = pc[i >> 1];
      unsigned short us = (i & 1) ? (unsigned short)(dw >> 16)
                                  : (unsigned short)(dw & 0xFFFFu);
      acc[i] = bf2f(us);
    }
    if (t < 1023) xaddr += 262144ULL;   // uniform step to next t's packet
    XLD2(pn, xaddr);

    // ---- MFMA: a-frags from swizzled LDS, b-frags from regs ----
    #pragma unroll
    for (int kk = 0; kk < 16; ++kk) {
      int b0 = (l15 * 1024 + kk * 64 + hi4 * 16) ^ ((l15 & 7) << 4);
      short8 a0 = *(const short8*)((const char*)hA + b0);
      acc = mfma16(a0, bw[kk], acc);
    }
    // ---- preact dump ----
    #pragma unroll
    for (int i = 0; i < 4; ++i)
      pre[g][hi4 * 4 + i][l15] = acc[i];
    __syncthreads();                // B2

    // ---- early issue: first-round polls for slot t+1 (non-own granules) ----
    if (t < 1023) {
      const unsigned short* hbn =
          hring + dbase + ((size_t)((t + 1) & 3) << 13);
      #pragma unroll
      for (int k = 0; k < 4; ++k)
        if (!((own >> k) & 1u)) PLD1(gb[k], voff[k], hbn);
    }

    // ---- combine (tid < 128): row r, local cols cq..cq+1 ----
    if (tid < 128) {
      float hv[2];
      #pragma unroll
      for (int i = 0; i < 2; ++i) {
        float fg = sigm(pre[0][r][cq + i]);
        float ig = sigm(pre[1][r][cq + i]);
        float gg = tanh_(pre[2][r][cq + i]);
        float og = sigm(pre[3][r][cq + i]);
        float c = fg * cst[i] + ig * gg;
        cst[i] = c;
        hv[i] = og * tanh_(c);
      }
      if (t < 1023) {
        unsigned int u0 = f2bf(hv[0]), u1 = f2bf(hv[1]);
        if (u0 == 0x8000u) u0 = 0;    // cleanse -0.0 (poison)
        if (u1 == 0x8000u) u1 = 0;
        unsigned int pk = u0 | (u1 << 16);
        const unsigned short* hbn =
            hring + dbase + ((size_t)((t + 1) & 3) << 13);
        asm volatile("global_store_dword %0, %1, %2 sc0 sc1"
                     :: "v"(vpub), "v"(pk), "s"(hbn) : "memory");
        // own slice direct to LDS for next step (skips the global RT)
        *(unsigned int*)((char*)hA + lown) = pk;
      } else {
        int b = dd * 16 + r, col = wgl * 16 + cq;
        out[(size_t)b * 512 + col] = hv[0];
        out[(size_t)b * 512 + col + 1] = hv[1];
        out[32768 + (size_t)b * 512 + col] = cst[0];
        out[32768 + (size_t)b * 512 + col + 1] = cst[1];
      }
    }
    pc = pn;
  }
}

// ---------------------------------------------------------------------------
extern "C" void kernel_launch(void* const* d_in, const int* in_sizes, int n_in,
                              void* d_out, int out_size, void* d_ws, size_t ws_size,
                              hipStream_t stream) {
  const float* x   = (const float*)d_in[0];
  const float* Wii = (const float*)d_in[1];
  const float* Whi = (const float*)d_in[2];
  const float* Wif = (const float*)d_in[3];
  const float* Whf = (const float*)d_in[4];
  const float* Wig = (const float*)d_in[5];
  const float* Whg = (const float*)d_in[6];
  const float* Wio = (const float*)d_in[7];
  const float* Who = (const float*)d_in[8];
  const float* bii = (const float*)d_in[9];
  const float* bhi = (const float*)d_in[10];
  const float* bif = (const float*)d_in[11];
  const float* bhf = (const float*)d_in[12];
  const float* big = (const float*)d_in[13];
  const float* bhg = (const float*)d_in[14];
  const float* bio = (const float*)d_in[15];
  const float* bho = (const float*)d_in[16];

  char* ws = (char*)d_ws;
  size_t off = 0;
  auto alloc = [&](size_t bytes) {
    size_t p = off; off = (off + bytes + 255) & ~(size_t)255; return p;
  };
  unsigned short* WxT  = (unsigned short*)(ws + alloc(2048UL * 512 * 2));
  unsigned short* WhT  = (unsigned short*)(ws + alloc(32UL * 64 * 512 * 2));
  float*          bias = (float*)        (ws + alloc(2048UL * 4));
  unsigned short* hring= (unsigned short*)(ws + alloc(4UL * 4 * 16 * 512 * 2));
  unsigned short* xpb  = (unsigned short*)(ws + alloc(1024UL * 64 * 2048 * 2));
  if (off > ws_size) return;  // insufficient workspace -> fail visibly

  lstm_prep<<<2048, 256, 0, stream>>>(Wif, Wii, Wig, Wio, Whf, Whi, Whg, Who,
                                      bif, bhf, bii, bhi, big, bhg, bio, bho,
                                      WxT, WhT, bias, hring);
  lstm_xproj<<<8192, 256, 0, stream>>>(x, WxT, bias, xpb);
  lstm_rec<<<128, 256, 0, stream>>>(xpb, WhT, hring, (float*)d_out);
}